// Round 5
// baseline (514.862 us; speedup 1.0000x reference)
//
#include <hip/hip_runtime.h>
#include <hip/hip_fp16.h>
#include <hip/hip_cooperative_groups.h>

namespace cg = cooperative_groups;

// GCN: out = Ahat*(relu(Ahat*(x@W1)+b1))@W2 + b2,  Ahat = D^-1/2 (A+I) D^-1/2
// N=100000, E=1600000, IN=256, HID=128, OUT=64, fp32 in/out.
// R5: dispatch-count attack. Entire CSR build (zero + W-transpose + bucket
//     hist + scan + scatter + per-bucket counting sort) fused into ONE
//     cooperative kernel (4 grid.sync()s replace 6 dispatch overheads).
//     Pipeline is now 5 dispatches: build_all, gemm1, agg1, gemm2, agg2.
//     agg1 edge loop unrolled x8; agg2 processes 2 nodes/wave (half-wave
//     per 64-col row). GEMMs stay fp16 MFMA (R3).

#define IN_DIM 256
#define HID_DIM 128
#define OUT_DIM 64
#define BSHIFT 7
#define MAXNB 1024  // supports N <= 131072

typedef _Float16 half8 __attribute__((ext_vector_type(8)));
typedef float floatx4 __attribute__((ext_vector_type(4)));

struct BuildParams {
  const int* src;
  const int* dst;
  int E, NB, N;
  int* bcnt;
  int* boff;   // NB+1
  int* bcur;   // NB
  int2* pairs; // E
  int* csr;    // E
  int* off;    // N+1
  float* dinv; // N
  const float* W1;
  const float* W2;
  __half* Wt1;
  __half* Wt2;
};

// One cooperative kernel: all build phases. 256 blocks x 256 threads
// (1 block/CU -> co-residency guaranteed).
__global__ __launch_bounds__(256) void build_all(BuildParams p) {
  cg::grid_group grid = cg::this_grid();
  __shared__ int sm[3 * MAXNB];  // 12 KB, reused per phase
  const int t = threadIdx.x, b = blockIdx.x, nblk = gridDim.x;
  const int gid = b * 256 + t, gsz = nblk * 256;

  // ---- phase 0: zero bucket counters + W^T fp16 conversions ----
  for (int i = gid; i < p.NB; i += gsz) p.bcnt[i] = 0;
  for (int i = gid; i < IN_DIM * HID_DIM; i += gsz) {
    int n = i / IN_DIM, k = i % IN_DIM;
    p.Wt1[i] = __float2half(p.W1[k * HID_DIM + n]);
  }
  for (int i = gid; i < HID_DIM * OUT_DIM; i += gsz) {
    int n = i / HID_DIM, k = i % HID_DIM;
    p.Wt2[i] = __float2half(p.W2[k * OUT_DIM + n]);
  }
  grid.sync();

  // ---- phase 1: global bucket histogram (LDS-privatized) ----
  {
    int* h = sm;
    for (int i = t; i < MAXNB; i += 256) h[i] = 0;
    __syncthreads();
    for (int i = gid; i < p.E; i += gsz) atomicAdd(&h[p.dst[i] >> BSHIFT], 1);
    __syncthreads();
    for (int i = t; i < p.NB; i += 256) {
      int v = h[i];
      if (v) atomicAdd(&p.bcnt[i], v);
    }
  }
  grid.sync();

  // ---- phase 2: scan bucket counts on block 0 ----
  if (b == 0) {
    int i0 = t * 4;
    int v0 = (i0 + 0 < p.NB) ? p.bcnt[i0 + 0] : 0;
    int v1 = (i0 + 1 < p.NB) ? p.bcnt[i0 + 1] : 0;
    int v2 = (i0 + 2 < p.NB) ? p.bcnt[i0 + 2] : 0;
    int v3 = (i0 + 3 < p.NB) ? p.bcnt[i0 + 3] : 0;
    int s = v0 + v1 + v2 + v3;
    sm[t] = s;
    __syncthreads();
    for (int st = 1; st < 256; st <<= 1) {
      int a = (t >= st) ? sm[t - st] : 0;
      __syncthreads();
      sm[t] += a;
      __syncthreads();
    }
    int ex = sm[t] - s;
    int r0 = ex, r1 = ex + v0, r2 = ex + v0 + v1, r3 = ex + v0 + v1 + v2;
    if (i0 + 0 < p.NB) { p.boff[i0 + 0] = r0; p.bcur[i0 + 0] = r0; }
    if (i0 + 1 < p.NB) { p.boff[i0 + 1] = r1; p.bcur[i0 + 1] = r1; }
    if (i0 + 2 < p.NB) { p.boff[i0 + 2] = r2; p.bcur[i0 + 2] = r2; }
    if (i0 + 3 < p.NB) { p.boff[i0 + 3] = r3; p.bcur[i0 + 3] = r3; }
    if (t == 0) {
      p.boff[p.NB] = p.E;
      p.off[p.N] = p.E;
    }
  }
  grid.sync();

  // ---- phase 3: scatter edges into bucket-contiguous pairs ----
  {
    int* h = sm;
    int* base = sm + MAXNB;
    int* cur = sm + 2 * MAXNB;
    for (int i = t; i < MAXNB; i += 256) h[i] = 0;
    __syncthreads();
    int chunk = (p.E + nblk - 1) / nblk;
    int cs = b * chunk, ce = min(p.E, cs + chunk);
    for (int i = cs + t; i < ce; i += 256) atomicAdd(&h[p.dst[i] >> BSHIFT], 1);
    __syncthreads();
    for (int i = t; i < p.NB; i += 256) {
      int c = h[i];
      base[i] = c ? atomicAdd(&p.bcur[i], c) : 0;
      cur[i] = 0;
    }
    __syncthreads();
    for (int i = cs + t; i < ce; i += 256) {
      int d = p.dst[i];
      int bk = d >> BSHIFT;
      int r = atomicAdd(&cur[bk], 1);
      p.pairs[base[bk] + r] = make_int2(p.src[i], d);
    }
  }
  grid.sync();

  // ---- phase 4: per-bucket counting sort -> csr/off/dinv ----
  {
    int* ldeg = sm;
    int* shs = sm + 128;
    int* lcur = sm + 256;
    for (int bk = b; bk < p.NB; bk += nblk) {
      __syncthreads();  // protect LDS reuse across iterations
      int n0 = bk << BSHIFT;
      int cnt = min(128, p.N - n0);
      if (t < 128) ldeg[t] = 0;
      __syncthreads();
      int e0 = p.boff[bk], e1 = p.boff[bk + 1];
      for (int e = e0 + t; e < e1; e += 256) atomicAdd(&ldeg[p.pairs[e].y - n0], 1);
      __syncthreads();
      int v = (t < 128) ? ldeg[t] : 0;
      if (t < 128) shs[t] = v;
      __syncthreads();
      for (int s = 1; s < 128; s <<= 1) {
        int a = (t < 128 && t >= s) ? shs[t - s] : 0;
        __syncthreads();
        if (t < 128) shs[t] += a;
        __syncthreads();
      }
      if (t < cnt) {
        int ex = shs[t] - v;
        p.off[n0 + t] = e0 + ex;
        p.dinv[n0 + t] = 1.0f / sqrtf((float)(v + 1));
        lcur[t] = ex;
      }
      __syncthreads();
      for (int e = e0 + t; e < e1; e += 256) {
        int2 pr = p.pairs[e];
        int r = atomicAdd(&lcur[pr.y - n0], 1);
        p.csr[e0 + r] = pr.x;
      }
    }
  }
}

// C[M x NC](fp16) = A[M x K] @ W[K x NC] via v_mfma_f32_16x16x32_f16.
template <int K, int NC, typename AT>
__global__ __launch_bounds__(256) void mfma_gemm(const AT* __restrict__ A,
                                                 const __half* __restrict__ Wt,
                                                 __half* __restrict__ C, int M) {
  constexpr int BK = 32;
  constexpr int STR = BK + 8;  // padded LDS row stride (halves) -> 2-way max
  constexpr int CT = NC / 16;
  __shared__ _Float16 As[128 * STR];
  __shared__ _Float16 Ws[NC * STR];
  int row0 = blockIdx.x * 128;
  int t = threadIdx.x;
  int wave = t >> 6, lane = t & 63, quad = lane >> 4, lr = lane & 15;
  floatx4 acc[2][CT] = {};
  int arow = t >> 1, ako = (t & 1) * 16;
  int grow = row0 + arow;

  for (int k0 = 0; k0 < K; k0 += BK) {
    {
      half8 h0 = {}, h1 = {};
      if (grow < M) {
        if constexpr (sizeof(AT) == 4) {
          const float4* ap = (const float4*)(A + (size_t)grow * K + k0 + ako);
          float4 v0 = ap[0], v1 = ap[1], v2 = ap[2], v3 = ap[3];
          h0[0] = (_Float16)v0.x; h0[1] = (_Float16)v0.y;
          h0[2] = (_Float16)v0.z; h0[3] = (_Float16)v0.w;
          h0[4] = (_Float16)v1.x; h0[5] = (_Float16)v1.y;
          h0[6] = (_Float16)v1.z; h0[7] = (_Float16)v1.w;
          h1[0] = (_Float16)v2.x; h1[1] = (_Float16)v2.y;
          h1[2] = (_Float16)v2.z; h1[3] = (_Float16)v2.w;
          h1[4] = (_Float16)v3.x; h1[5] = (_Float16)v3.y;
          h1[6] = (_Float16)v3.z; h1[7] = (_Float16)v3.w;
        } else {
          const half8* ap = (const half8*)(A + (size_t)grow * K + k0 + ako);
          h0 = ap[0];
          h1 = ap[1];
        }
      }
      *(half8*)&As[arow * STR + ako] = h0;
      *(half8*)&As[arow * STR + ako + 8] = h1;
    }
    if constexpr (NC == 128) {
      int r = t >> 1, ko = (t & 1) * 16;
      const half8* wp = (const half8*)(Wt + (size_t)r * K + k0 + ko);
      *(half8*)&Ws[r * STR + ko] = wp[0];
      *(half8*)&Ws[r * STR + ko + 8] = wp[1];
    } else {  // NC == 64
      int r = t >> 2, ko = (t & 3) * 8;
      *(half8*)&Ws[r * STR + ko] = *(const half8*)(Wt + (size_t)r * K + k0 + ko);
    }
    __syncthreads();
    {
      int a_off = (wave * 32 + lr) * STR + quad * 8;
      half8 a0 = *(const half8*)&As[a_off];
      half8 a1 = *(const half8*)&As[a_off + 16 * STR];
      int b_off = lr * STR + quad * 8;
#pragma unroll
      for (int ct = 0; ct < CT; ct++) {
        half8 bfr = *(const half8*)&Ws[b_off + ct * 16 * STR];
        acc[0][ct] = __builtin_amdgcn_mfma_f32_16x16x32_f16(a0, bfr, acc[0][ct], 0, 0, 0);
        acc[1][ct] = __builtin_amdgcn_mfma_f32_16x16x32_f16(a1, bfr, acc[1][ct], 0, 0, 0);
      }
    }
    __syncthreads();
  }
#pragma unroll
  for (int rt = 0; rt < 2; rt++) {
    int rbase = row0 + wave * 32 + rt * 16 + quad * 4;
#pragma unroll
    for (int ct = 0; ct < CT; ct++) {
      int col = ct * 16 + lr;
#pragma unroll
      for (int i = 0; i < 4; i++) {
        int row = rbase + i;
        if (row < M) C[(size_t)row * NC + col] = __float2half(acc[rt][ct][i]);
      }
    }
  }
}

// agg layer 1: one wave per node, NC=128, lane covers 2 cols (__half2).
// out fp16 = relu(dinv[n]*(sum dinv[s]*h[s,:] + dinv[n]*h[n,:]) + b). x8 unroll.
__global__ __launch_bounds__(256) void agg1_kernel(const __half* __restrict__ h,
                                                   const int* __restrict__ off,
                                                   const int* __restrict__ csr,
                                                   const float* __restrict__ dinv,
                                                   const float* __restrict__ bias,
                                                   __half* __restrict__ out, int N) {
  constexpr int NC = HID_DIM;
  int node = blockIdx.x * 4 + (threadIdx.x >> 6);
  int lane = threadIdx.x & 63;
  if (node >= N) return;
  int c = lane * 2;
  float di = dinv[node];
  float a0 = 0.f, a1 = 0.f;
  auto gather = [&](int sidx, float w) {
    __half2 hv = *(const __half2*)(h + (size_t)sidx * NC + c);
    float2 f = __half22float2(hv);
    a0 += w * f.x;
    a1 += w * f.y;
  };
  gather(node, di);  // self-loop (x di again at the end)
  int e0 = off[node], e1 = off[node + 1];
  int e = e0;
  for (; e + 8 <= e1; e += 8) {
    int s0 = csr[e], s1 = csr[e + 1], s2 = csr[e + 2], s3 = csr[e + 3];
    int s4 = csr[e + 4], s5 = csr[e + 5], s6 = csr[e + 6], s7 = csr[e + 7];
    float w0 = dinv[s0], w1 = dinv[s1], w2 = dinv[s2], w3 = dinv[s3];
    float w4 = dinv[s4], w5 = dinv[s5], w6 = dinv[s6], w7 = dinv[s7];
    gather(s0, w0); gather(s1, w1); gather(s2, w2); gather(s3, w3);
    gather(s4, w4); gather(s5, w5); gather(s6, w6); gather(s7, w7);
  }
  for (; e + 4 <= e1; e += 4) {
    int s0 = csr[e], s1 = csr[e + 1], s2 = csr[e + 2], s3 = csr[e + 3];
    float w0 = dinv[s0], w1 = dinv[s1], w2 = dinv[s2], w3 = dinv[s3];
    gather(s0, w0); gather(s1, w1); gather(s2, w2); gather(s3, w3);
  }
  for (; e < e1; e++) {
    int s = csr[e];
    gather(s, dinv[s]);
  }
  float r0 = fmaxf(di * a0 + bias[c], 0.f);
  float r1 = fmaxf(di * a1 + bias[c + 1], 0.f);
  *(__half2*)(out + (size_t)node * NC + c) = __floats2half2_rn(r0, r1);
}

// agg layer 2: NC=64 -> HALF-wave per node (32 lanes x __half2 = 64 cols).
// out fp32 = dinv[n]*(sum dinv[s]*h[s,:] + dinv[n]*h[n,:]) + b.  x4 unroll.
__global__ __launch_bounds__(256) void agg2_kernel(const __half* __restrict__ h,
                                                   const int* __restrict__ off,
                                                   const int* __restrict__ csr,
                                                   const float* __restrict__ dinv,
                                                   const float* __restrict__ bias,
                                                   float* __restrict__ out, int N) {
  constexpr int NC = OUT_DIM;
  int node = blockIdx.x * 8 + (threadIdx.x >> 5);
  int hl = threadIdx.x & 31;
  if (node >= N) return;
  int c = hl * 2;
  float di = dinv[node];
  float a0 = 0.f, a1 = 0.f;
  auto gather = [&](int sidx, float w) {
    __half2 hv = *(const __half2*)(h + (size_t)sidx * NC + c);
    float2 f = __half22float2(hv);
    a0 += w * f.x;
    a1 += w * f.y;
  };
  gather(node, di);
  int e0 = off[node], e1 = off[node + 1];
  int e = e0;
  for (; e + 4 <= e1; e += 4) {
    int s0 = csr[e], s1 = csr[e + 1], s2 = csr[e + 2], s3 = csr[e + 3];
    float w0 = dinv[s0], w1 = dinv[s1], w2 = dinv[s2], w3 = dinv[s3];
    gather(s0, w0); gather(s1, w1); gather(s2, w2); gather(s3, w3);
  }
  for (; e < e1; e++) {
    int s = csr[e];
    gather(s, dinv[s]);
  }
  out[(size_t)node * NC + c] = di * a0 + bias[c];
  out[(size_t)node * NC + c + 1] = di * a1 + bias[c + 1];
}

extern "C" void kernel_launch(void* const* d_in, const int* in_sizes, int n_in,
                              void* d_out, int out_size, void* d_ws, size_t ws_size,
                              hipStream_t stream) {
  const float* x  = (const float*)d_in[0];
  const int*   ei = (const int*)d_in[1];
  const float* W1 = (const float*)d_in[2];
  const float* b1 = (const float*)d_in[3];
  const float* W2 = (const float*)d_in[4];
  const float* b2 = (const float*)d_in[5];
  float* out = (float*)d_out;

  int N = in_sizes[0] / IN_DIM;
  int E = in_sizes[1] / 2;
  int NB = (N + 127) >> BSHIFT;  // 782 for N=100000 (<= MAXNB)

  char* p = (char*)d_ws;
  auto alloc = [&](size_t bytes) {
    char* q = p;
    p += (bytes + 255) & ~(size_t)255;
    return q;
  };
  int*    bcnt  = (int*)alloc((size_t)NB * 4);
  int*    boff  = (int*)alloc((size_t)(NB + 1) * 4);
  int*    bcur  = (int*)alloc((size_t)NB * 4);
  int2*   pairs = (int2*)alloc((size_t)E * 8);
  int*    csr   = (int*)alloc((size_t)E * 4);
  int*    off   = (int*)alloc((size_t)(N + 1) * 4);
  float*  dinv  = (float*)alloc((size_t)N * 4);
  __half* h1    = (__half*)alloc((size_t)N * HID_DIM * 2);  // reused as h2
  __half* z16   = (__half*)alloc((size_t)N * HID_DIM * 2);
  __half* Wt1   = (__half*)alloc((size_t)IN_DIM * HID_DIM * 2);
  __half* Wt2   = (__half*)alloc((size_t)HID_DIM * OUT_DIM * 2);
  __half* h2    = h1;
  (void)ws_size; (void)n_in; (void)out_size;

  BuildParams bp;
  bp.src = ei;
  bp.dst = ei + E;
  bp.E = E; bp.NB = NB; bp.N = N;
  bp.bcnt = bcnt; bp.boff = boff; bp.bcur = bcur;
  bp.pairs = pairs; bp.csr = csr; bp.off = off; bp.dinv = dinv;
  bp.W1 = W1; bp.W2 = W2; bp.Wt1 = Wt1; bp.Wt2 = Wt2;
  void* args[] = {&bp};
  hipLaunchCooperativeKernel((void*)build_all, dim3(256), dim3(256), args, 0, stream);

  int gb = (N + 127) / 128;
  mfma_gemm<IN_DIM, HID_DIM, float><<<gb, 256, 0, stream>>>(x, Wt1, h1, N);
  agg1_kernel<<<(N + 3) / 4, 256, 0, stream>>>(h1, off, csr, dinv, b1, z16, N);

  mfma_gemm<HID_DIM, OUT_DIM, __half><<<gb, 256, 0, stream>>>(z16, Wt2, h2, N);
  agg2_kernel<<<(N + 7) / 8, 256, 0, stream>>>(h2, off, csr, dinv, b2, out, N);
}

// Round 6
// 402.166 us; speedup vs baseline: 1.2802x; 1.2802x over previous
//
#include <hip/hip_runtime.h>
#include <hip/hip_fp16.h>

// GCN: out = Ahat*(relu(Ahat*(x@W1)+b1))@W2 + b2,  Ahat = D^-1/2 (A+I) D^-1/2
// N=100000, E=1600000, IN=256, HID=128, OUT=64, fp32 in/out.
// R6: revert R5's cooperative fusion (launch overhead + parallelism starvation).
//     Build = separate kernels again (R4 structure) with:
//       - pairs packed to 4B: (src<<7)|(dst&127)  [src < 2^17]
//       - scatter kernel LDS-stages its chunk (counting sort) and writes
//         bucket-runs in sorted order -> coalesced ~32B segments, not 4B scatter
//       - W-transpose folded into hist kernel (2 fewer dispatches)
//     agg1 x8 unroll; agg2 half-wave/node. GEMMs fp16 MFMA (R3).

#define IN_DIM 256
#define HID_DIM 128
#define OUT_DIM 64
#define BSHIFT 7
#define MAXNB 1024      // supports N <= 131072
#define STAGE_CAP 8192  // max edges staged per scatter block (32 KB LDS)

typedef _Float16 half8 __attribute__((ext_vector_type(8)));
typedef float floatx4 __attribute__((ext_vector_type(4)));

// ---- build A: bucket histogram (LDS-privatized) + W^T fp16 conversion ----
__global__ __launch_bounds__(256) void bucket_hist(const int* __restrict__ dst, int E,
                                                   int NB, int* __restrict__ bcnt,
                                                   const float* __restrict__ W1,
                                                   const float* __restrict__ W2,
                                                   __half* __restrict__ Wt1,
                                                   __half* __restrict__ Wt2) {
  __shared__ int h[MAXNB];
  int t = threadIdx.x;
  int gid = blockIdx.x * 256 + t, gsz = gridDim.x * 256;
  // fold in the (tiny) weight transposes
  for (int i = gid; i < IN_DIM * HID_DIM; i += gsz) {
    int n = i / IN_DIM, k = i % IN_DIM;
    Wt1[i] = __float2half(W1[k * HID_DIM + n]);
  }
  for (int i = gid; i < HID_DIM * OUT_DIM; i += gsz) {
    int n = i / HID_DIM, k = i % HID_DIM;
    Wt2[i] = __float2half(W2[k * OUT_DIM + n]);
  }
  for (int i = t; i < MAXNB; i += 256) h[i] = 0;
  __syncthreads();
  for (int i = gid; i < E; i += gsz) atomicAdd(&h[dst[i] >> BSHIFT], 1);
  __syncthreads();
  for (int i = t; i < NB; i += 256) {
    int v = h[i];
    if (v) atomicAdd(&bcnt[i], v);
  }
}

// ---- build B: scan bucket counts; init global cursors; off[N]=E ----
__global__ __launch_bounds__(1024) void bucket_scan(const int* __restrict__ bcnt, int NB,
                                                    int E, int* __restrict__ boff,
                                                    int* __restrict__ bcur,
                                                    int* __restrict__ off, int N) {
  __shared__ int sh[1024];
  int t = threadIdx.x;
  int v = (t < NB) ? bcnt[t] : 0;
  sh[t] = v;
  __syncthreads();
  for (int s = 1; s < 1024; s <<= 1) {
    int a = (t >= s) ? sh[t - s] : 0;
    __syncthreads();
    sh[t] += a;
    __syncthreads();
  }
  if (t < NB) {
    int ex = sh[t] - v;
    boff[t] = ex;
    bcur[t] = ex;
  }
  if (t == 0) {
    boff[NB] = E;
    off[N] = E;
  }
}

// ---- build C: LDS-staged counting sort of each chunk, coalesced writeout ----
// pairs[g] = (src<<7)|(dst&127), bucket-contiguous.
__global__ __launch_bounds__(256) void bucket_scatter(const int* __restrict__ src,
                                                      const int* __restrict__ dst, int E,
                                                      int NB, int* __restrict__ bcur,
                                                      int* __restrict__ pairs) {
  __shared__ int hist[MAXNB];
  __shared__ int base_l[MAXNB + 1];  // exclusive scan of hist (LDS slot base)
  __shared__ int base_g[MAXNB];     // this block's run base in global pairs[]
  __shared__ int cur[MAXNB];
  __shared__ int sm[256];
  __shared__ int stage[STAGE_CAP];
  int t = threadIdx.x;
  int chunk = (E + gridDim.x - 1) / gridDim.x;
  int s0 = blockIdx.x * chunk, s1 = min(E, s0 + chunk);
  int cnt = s1 - s0;  // <= STAGE_CAP by launch config

  for (int i = t; i < MAXNB; i += 256) hist[i] = 0;
  __syncthreads();
  for (int i = s0 + t; i < s1; i += 256) atomicAdd(&hist[dst[i] >> BSHIFT], 1);
  __syncthreads();
  // scan 1024 hist entries with 256 threads (4 each)
  {
    int i0 = t * 4;
    int v0 = hist[i0], v1 = hist[i0 + 1], v2 = hist[i0 + 2], v3 = hist[i0 + 3];
    int s = v0 + v1 + v2 + v3;
    sm[t] = s;
    __syncthreads();
    for (int st = 1; st < 256; st <<= 1) {
      int a = (t >= st) ? sm[t - st] : 0;
      __syncthreads();
      sm[t] += a;
      __syncthreads();
    }
    int ex = sm[t] - s;
    base_l[i0] = ex;
    base_l[i0 + 1] = ex + v0;
    base_l[i0 + 2] = ex + v0 + v1;
    base_l[i0 + 3] = ex + v0 + v1 + v2;
    cur[i0] = ex;
    cur[i0 + 1] = ex + v0;
    cur[i0 + 2] = ex + v0 + v1;
    cur[i0 + 3] = ex + v0 + v1 + v2;
    if (v0) base_g[i0] = atomicAdd(&bcur[i0], v0);
    if (v1) base_g[i0 + 1] = atomicAdd(&bcur[i0 + 1], v1);
    if (v2) base_g[i0 + 2] = atomicAdd(&bcur[i0 + 2], v2);
    if (v3) base_g[i0 + 3] = atomicAdd(&bcur[i0 + 3], v3);
    if (t == 0) base_l[MAXNB] = cnt;
  }
  __syncthreads();
  // rank-scatter into LDS stage (packed payload)
  for (int i = s0 + t; i < s1; i += 256) {
    int d = dst[i];
    int bk = d >> BSHIFT;
    int r = atomicAdd(&cur[bk], 1);
    stage[r] = (src[i] << BSHIFT) | (d & ((1 << BSHIFT) - 1));
  }
  __syncthreads();
  // coalesced writeout: slot j -> bucket via binary search on base_l
  for (int j = t; j < cnt; j += 256) {
    int lo = 0, hi = MAXNB;
    while (hi - lo > 1) {
      int mid = (lo + hi) >> 1;
      if (base_l[mid] <= j) lo = mid;
      else hi = mid;
    }
    pairs[base_g[lo] + (j - base_l[lo])] = stage[j];
  }
}

// ---- build D: per-bucket counting sort -> csr/off/dinv ----
__global__ __launch_bounds__(256) void bucket_csr(const int* __restrict__ pairs,
                                                  const int* __restrict__ boff, int N,
                                                  int* __restrict__ csr,
                                                  int* __restrict__ off,
                                                  float* __restrict__ dinv) {
  int b = blockIdx.x;
  int t = threadIdx.x;
  int n0 = b << BSHIFT;
  int cnt = min(128, N - n0);
  __shared__ int ldeg[128], sh[128], lcur[128];
  if (t < 128) ldeg[t] = 0;
  __syncthreads();
  int e0 = boff[b], e1 = boff[b + 1];
  for (int e = e0 + t; e < e1; e += 256) atomicAdd(&ldeg[pairs[e] & 127], 1);
  __syncthreads();
  int v = (t < 128) ? ldeg[t] : 0;
  if (t < 128) sh[t] = v;
  __syncthreads();
  for (int s = 1; s < 128; s <<= 1) {
    int a = (t < 128 && t >= s) ? sh[t - s] : 0;
    __syncthreads();
    if (t < 128) sh[t] += a;
    __syncthreads();
  }
  if (t < cnt) {
    int ex = sh[t] - v;
    off[n0 + t] = e0 + ex;
    dinv[n0 + t] = 1.0f / sqrtf((float)(v + 1));
    lcur[t] = ex;
  }
  __syncthreads();
  for (int e = e0 + t; e < e1; e += 256) {
    int pk = pairs[e];
    int r = atomicAdd(&lcur[pk & 127], 1);
    csr[e0 + r] = pk >> BSHIFT;
  }
}

// C[M x NC](fp16) = A[M x K] @ W[K x NC] via v_mfma_f32_16x16x32_f16.
template <int K, int NC, typename AT>
__global__ __launch_bounds__(256) void mfma_gemm(const AT* __restrict__ A,
                                                 const __half* __restrict__ Wt,
                                                 __half* __restrict__ C, int M) {
  constexpr int BK = 32;
  constexpr int STR = BK + 8;  // padded LDS row stride (halves) -> 2-way max
  constexpr int CT = NC / 16;
  __shared__ _Float16 As[128 * STR];
  __shared__ _Float16 Ws[NC * STR];
  int row0 = blockIdx.x * 128;
  int t = threadIdx.x;
  int wave = t >> 6, lane = t & 63, quad = lane >> 4, lr = lane & 15;
  floatx4 acc[2][CT] = {};
  int arow = t >> 1, ako = (t & 1) * 16;
  int grow = row0 + arow;

  for (int k0 = 0; k0 < K; k0 += BK) {
    {
      half8 h0 = {}, h1 = {};
      if (grow < M) {
        if constexpr (sizeof(AT) == 4) {
          const float4* ap = (const float4*)(A + (size_t)grow * K + k0 + ako);
          float4 v0 = ap[0], v1 = ap[1], v2 = ap[2], v3 = ap[3];
          h0[0] = (_Float16)v0.x; h0[1] = (_Float16)v0.y;
          h0[2] = (_Float16)v0.z; h0[3] = (_Float16)v0.w;
          h0[4] = (_Float16)v1.x; h0[5] = (_Float16)v1.y;
          h0[6] = (_Float16)v1.z; h0[7] = (_Float16)v1.w;
          h1[0] = (_Float16)v2.x; h1[1] = (_Float16)v2.y;
          h1[2] = (_Float16)v2.z; h1[3] = (_Float16)v2.w;
          h1[4] = (_Float16)v3.x; h1[5] = (_Float16)v3.y;
          h1[6] = (_Float16)v3.z; h1[7] = (_Float16)v3.w;
        } else {
          const half8* ap = (const half8*)(A + (size_t)grow * K + k0 + ako);
          h0 = ap[0];
          h1 = ap[1];
        }
      }
      *(half8*)&As[arow * STR + ako] = h0;
      *(half8*)&As[arow * STR + ako + 8] = h1;
    }
    if constexpr (NC == 128) {
      int r = t >> 1, ko = (t & 1) * 16;
      const half8* wp = (const half8*)(Wt + (size_t)r * K + k0 + ko);
      *(half8*)&Ws[r * STR + ko] = wp[0];
      *(half8*)&Ws[r * STR + ko + 8] = wp[1];
    } else {  // NC == 64
      int r = t >> 2, ko = (t & 3) * 8;
      *(half8*)&Ws[r * STR + ko] = *(const half8*)(Wt + (size_t)r * K + k0 + ko);
    }
    __syncthreads();
    {
      int a_off = (wave * 32 + lr) * STR + quad * 8;
      half8 a0 = *(const half8*)&As[a_off];
      half8 a1 = *(const half8*)&As[a_off + 16 * STR];
      int b_off = lr * STR + quad * 8;
#pragma unroll
      for (int ct = 0; ct < CT; ct++) {
        half8 bfr = *(const half8*)&Ws[b_off + ct * 16 * STR];
        acc[0][ct] = __builtin_amdgcn_mfma_f32_16x16x32_f16(a0, bfr, acc[0][ct], 0, 0, 0);
        acc[1][ct] = __builtin_amdgcn_mfma_f32_16x16x32_f16(a1, bfr, acc[1][ct], 0, 0, 0);
      }
    }
    __syncthreads();
  }
#pragma unroll
  for (int rt = 0; rt < 2; rt++) {
    int rbase = row0 + wave * 32 + rt * 16 + quad * 4;
#pragma unroll
    for (int ct = 0; ct < CT; ct++) {
      int col = ct * 16 + lr;
#pragma unroll
      for (int i = 0; i < 4; i++) {
        int row = rbase + i;
        if (row < M) C[(size_t)row * NC + col] = __float2half(acc[rt][ct][i]);
      }
    }
  }
}

// agg layer 1: one wave per node, NC=128, lane covers 2 cols (__half2). x8 unroll.
__global__ __launch_bounds__(256) void agg1_kernel(const __half* __restrict__ h,
                                                   const int* __restrict__ off,
                                                   const int* __restrict__ csr,
                                                   const float* __restrict__ dinv,
                                                   const float* __restrict__ bias,
                                                   __half* __restrict__ out, int N) {
  constexpr int NC = HID_DIM;
  int node = blockIdx.x * 4 + (threadIdx.x >> 6);
  int lane = threadIdx.x & 63;
  if (node >= N) return;
  int c = lane * 2;
  float di = dinv[node];
  float a0 = 0.f, a1 = 0.f;
  auto gather = [&](int sidx, float w) {
    __half2 hv = *(const __half2*)(h + (size_t)sidx * NC + c);
    float2 f = __half22float2(hv);
    a0 += w * f.x;
    a1 += w * f.y;
  };
  gather(node, di);  // self-loop (x di again at the end)
  int e0 = off[node], e1 = off[node + 1];
  int e = e0;
  for (; e + 8 <= e1; e += 8) {
    int s0 = csr[e], s1 = csr[e + 1], s2 = csr[e + 2], s3 = csr[e + 3];
    int s4 = csr[e + 4], s5 = csr[e + 5], s6 = csr[e + 6], s7 = csr[e + 7];
    float w0 = dinv[s0], w1 = dinv[s1], w2 = dinv[s2], w3 = dinv[s3];
    float w4 = dinv[s4], w5 = dinv[s5], w6 = dinv[s6], w7 = dinv[s7];
    gather(s0, w0); gather(s1, w1); gather(s2, w2); gather(s3, w3);
    gather(s4, w4); gather(s5, w5); gather(s6, w6); gather(s7, w7);
  }
  for (; e + 4 <= e1; e += 4) {
    int s0 = csr[e], s1 = csr[e + 1], s2 = csr[e + 2], s3 = csr[e + 3];
    float w0 = dinv[s0], w1 = dinv[s1], w2 = dinv[s2], w3 = dinv[s3];
    gather(s0, w0); gather(s1, w1); gather(s2, w2); gather(s3, w3);
  }
  for (; e < e1; e++) {
    int s = csr[e];
    gather(s, dinv[s]);
  }
  float r0 = fmaxf(di * a0 + bias[c], 0.f);
  float r1 = fmaxf(di * a1 + bias[c + 1], 0.f);
  *(__half2*)(out + (size_t)node * NC + c) = __floats2half2_rn(r0, r1);
}

// agg layer 2: NC=64 -> half-wave per node (32 lanes x __half2). x4 unroll.
__global__ __launch_bounds__(256) void agg2_kernel(const __half* __restrict__ h,
                                                   const int* __restrict__ off,
                                                   const int* __restrict__ csr,
                                                   const float* __restrict__ dinv,
                                                   const float* __restrict__ bias,
                                                   float* __restrict__ out, int N) {
  constexpr int NC = OUT_DIM;
  int node = blockIdx.x * 8 + (threadIdx.x >> 5);
  int hl = threadIdx.x & 31;
  if (node >= N) return;
  int c = hl * 2;
  float di = dinv[node];
  float a0 = 0.f, a1 = 0.f;
  auto gather = [&](int sidx, float w) {
    __half2 hv = *(const __half2*)(h + (size_t)sidx * NC + c);
    float2 f = __half22float2(hv);
    a0 += w * f.x;
    a1 += w * f.y;
  };
  gather(node, di);
  int e0 = off[node], e1 = off[node + 1];
  int e = e0;
  for (; e + 4 <= e1; e += 4) {
    int s0 = csr[e], s1 = csr[e + 1], s2 = csr[e + 2], s3 = csr[e + 3];
    float w0 = dinv[s0], w1 = dinv[s1], w2 = dinv[s2], w3 = dinv[s3];
    gather(s0, w0); gather(s1, w1); gather(s2, w2); gather(s3, w3);
  }
  for (; e < e1; e++) {
    int s = csr[e];
    gather(s, dinv[s]);
  }
  out[(size_t)node * NC + c] = di * a0 + bias[c];
  out[(size_t)node * NC + c + 1] = di * a1 + bias[c + 1];
}

extern "C" void kernel_launch(void* const* d_in, const int* in_sizes, int n_in,
                              void* d_out, int out_size, void* d_ws, size_t ws_size,
                              hipStream_t stream) {
  const float* x  = (const float*)d_in[0];
  const int*   ei = (const int*)d_in[1];
  const float* W1 = (const float*)d_in[2];
  const float* b1 = (const float*)d_in[3];
  const float* W2 = (const float*)d_in[4];
  const float* b2 = (const float*)d_in[5];
  float* out = (float*)d_out;

  int N = in_sizes[0] / IN_DIM;
  int E = in_sizes[1] / 2;
  const int* src = ei;
  const int* dst = ei + E;
  int NB = (N + 127) >> BSHIFT;  // 782 for N=100000 (<= MAXNB)

  char* p = (char*)d_ws;
  auto alloc = [&](size_t bytes) {
    char* q = p;
    p += (bytes + 255) & ~(size_t)255;
    return q;
  };
  int*    bcnt  = (int*)alloc((size_t)NB * 4);
  int*    boff  = (int*)alloc((size_t)(NB + 1) * 4);
  int*    bcur  = (int*)alloc((size_t)NB * 4);
  int*    pairs = (int*)alloc((size_t)E * 4);   // packed (src<<7)|(dst&127)
  int*    csr   = (int*)alloc((size_t)E * 4);
  int*    off   = (int*)alloc((size_t)(N + 1) * 4);
  float*  dinv  = (float*)alloc((size_t)N * 4);
  __half* h1    = (__half*)alloc((size_t)N * HID_DIM * 2);  // reused as h2
  __half* z16   = (__half*)alloc((size_t)N * HID_DIM * 2);
  __half* Wt1   = (__half*)alloc((size_t)IN_DIM * HID_DIM * 2);
  __half* Wt2   = (__half*)alloc((size_t)HID_DIM * OUT_DIM * 2);
  __half* h2    = h1;
  (void)ws_size; (void)n_in; (void)out_size;

  hipMemsetAsync(bcnt, 0, (size_t)NB * 4, stream);

  bucket_hist<<<256, 256, 0, stream>>>(dst, E, NB, bcnt, W1, W2, Wt1, Wt2);
  bucket_scan<<<1, 1024, 0, stream>>>(bcnt, NB, E, boff, bcur, off, N);
  int sblk = max(256, (E + STAGE_CAP - 1) / STAGE_CAP);  // chunk <= STAGE_CAP
  bucket_scatter<<<sblk, 256, 0, stream>>>(src, dst, E, NB, bcur, pairs);
  bucket_csr<<<NB, 256, 0, stream>>>(pairs, boff, N, csr, off, dinv);

  int gb = (N + 127) / 128;
  mfma_gemm<IN_DIM, HID_DIM, float><<<gb, 256, 0, stream>>>(x, Wt1, h1, N);
  agg1_kernel<<<(N + 3) / 4, 256, 0, stream>>>(h1, off, csr, dinv, b1, z16, N);

  mfma_gemm<HID_DIM, OUT_DIM, __half><<<gb, 256, 0, stream>>>(z16, Wt2, h2, N);
  agg2_kernel<<<(N + 7) / 8, 256, 0, stream>>>(h2, off, csr, dinv, b2, out, N);
}